// Round 1
// baseline (886.432 us; speedup 1.0000x reference)
//
#include <hip/hip_runtime.h>
#include <math.h>

#define NEGF -1000000000.0f
#define EPSF 1e-7f

// B=32, T=256, IN=64, H=128, 4H=512, TOP_K=5

__device__ __forceinline__ float sigmoidf_(float x) {
  return 1.0f / (1.0f + expf(-x));
}

// Kernel 1: xw[b][t][g] = sum_k x[b][t][k] * W_ih[g][k] + (b_ih[g]+b_hh[g])
// grid (16, 32) = (T/16, B), block 512 (one thread per gate)
__global__ __launch_bounds__(512) void xw_kernel(
    const float* __restrict__ x, const float* __restrict__ W_ih,
    const float* __restrict__ b_ih, const float* __restrict__ b_hh,
    float* __restrict__ xw)
{
  const int TT = 16;
  const int t0 = blockIdx.x * TT;
  const int b  = blockIdx.y;
  __shared__ float sx[16][64];
  for (int idx = threadIdx.x; idx < TT * 64; idx += 512) {
    int tt = idx >> 6, k = idx & 63;
    sx[tt][k] = x[(size_t)(b * 256 + t0 + tt) * 64 + k];
  }
  __syncthreads();
  const int g = threadIdx.x;
  float w[64];
  {
    const float4* wr = (const float4*)(W_ih + g * 64);
    #pragma unroll
    for (int q = 0; q < 16; ++q) {
      float4 v = wr[q];
      w[4*q+0] = v.x; w[4*q+1] = v.y; w[4*q+2] = v.z; w[4*q+3] = v.w;
    }
  }
  const float bias = b_ih[g] + b_hh[g];
  for (int tt = 0; tt < TT; ++tt) {
    float acc = bias;
    #pragma unroll
    for (int k = 0; k < 64; ++k) acc = fmaf(w[k], sx[tt][k], acc);
    xw[(size_t)(b * 256 + t0 + tt) * 512 + g] = acc;
  }
}

// Kernel 2: full recurrence, one block per batch element.
// 512 threads; thread g owns gate g and keeps W_hh row g in 128 VGPRs.
__global__ __launch_bounds__(512, 2) void lstm_attn(
    const float* __restrict__ xw, const float* __restrict__ W_hh,
    const float* __restrict__ w_t, float* __restrict__ h_old,
    float* __restrict__ out)
{
  const int b    = blockIdx.x;
  const int tid  = threadIdx.x;
  const int lane = tid & 63;
  const int wid  = tid >> 6;

  __shared__ float sh_g[512];
  __shared__ float sh_h[128];
  __shared__ float sh_hcell[128];
  __shared__ float sh_d[257];
  __shared__ float sh_wa[128];
  __shared__ float sh_wb[128];
  __shared__ float sh_top5[5];
  __shared__ float sh_redA[8];
  __shared__ float sh_redW[8];
  __shared__ float sh_redD[8];
  __shared__ int   sh_nnz;
  __shared__ int   sh_cidx[8];
  __shared__ float sh_cw[8];

  // preload W_hh row (one-time; stays in VGPRs, fully-unrolled accesses)
  float whr[128];
  {
    const float4* wr = (const float4*)(W_hh + (size_t)tid * 128);
    #pragma unroll
    for (int q = 0; q < 32; ++q) {
      float4 v = wr[q];
      whr[4*q+0] = v.x; whr[4*q+1] = v.y; whr[4*q+2] = v.z; whr[4*q+3] = v.w;
    }
  }
  if (tid < 128) {
    sh_h[tid]  = 0.0f;
    sh_wa[tid] = w_t[tid];
    sh_wb[tid] = w_t[128 + tid];
    h_old[((size_t)b * 257 + 0) * 128 + tid] = 0.0f;  // row 0 = zeros (ws is poisoned)
  }
  if (tid == 0) {
    sh_d[0] = 0.0f;                       // tanh(0)·w_b
    sh_top5[0] = 0.0f;                    // top-5 of {d[0]}
    sh_top5[1] = sh_top5[2] = sh_top5[3] = sh_top5[4] = NEGF;
  }
  float c_reg = 0.0f;  // c[j] lives in thread j (tid<128)
  __syncthreads();

  const float* xwb = xw + (size_t)b * 256 * 512;
  float* hob = h_old + (size_t)b * 257 * 128;

  float xnext = xwb[tid];  // prefetch step 0

  for (int i = 0; i < 256; ++i) {
    const int rem = i + 1;

    // ---- Phase A: gates g = xw + W_hh · h_prev ----
    float acc0 = xnext, acc1 = 0.0f, acc2 = 0.0f, acc3 = 0.0f;
    #pragma unroll
    for (int k = 0; k < 128; k += 4) {
      acc0 = fmaf(whr[k+0], sh_h[k+0], acc0);
      acc1 = fmaf(whr[k+1], sh_h[k+1], acc1);
      acc2 = fmaf(whr[k+2], sh_h[k+2], acc2);
      acc3 = fmaf(whr[k+3], sh_h[k+3], acc3);
    }
    sh_g[tid] = (acc0 + acc1) + (acc2 + acc3);
    if (i < 255) xnext = xwb[(size_t)(i + 1) * 512 + tid];  // prefetch next step
    __syncthreads();                                        // S1

    // ---- Phase B: LSTM cell + a = tanh(h_cell)·w_a partial ----
    float pa = 0.0f;
    if (tid < 128) {
      float ig = sigmoidf_(sh_g[tid]);
      float fg = sigmoidf_(sh_g[tid + 128]);
      float gg = tanhf(sh_g[tid + 256]);
      float og = sigmoidf_(sh_g[tid + 384]);
      c_reg = fg * c_reg + ig * gg;
      float hc = og * tanhf(c_reg);
      sh_hcell[tid] = hc;
      pa = tanhf(hc) * sh_wa[tid];
    }
    #pragma unroll
    for (int off = 32; off > 0; off >>= 1) pa += __shfl_down(pa, off, 64);
    if (lane == 0) sh_redA[wid] = pa;
    if (tid == 0) sh_nnz = 0;
    __syncthreads();                                        // S2
    const float a = ((sh_redA[0] + sh_redA[1]) + (sh_redA[2] + sh_redA[3]))
                  + ((sh_redA[4] + sh_redA[5]) + (sh_redA[6] + sh_redA[7]));

    // ---- Phase C: scores, sparse weights ----
    const float d5    = sh_top5[4];
    const float delta = (a + d5) + EPSF;   // matches ref: topk_val + EPS
    float s_t = 0.0f, w = 0.0f;
    if (tid < rem) {                       // rem <= 256 so tid<256 implied
      s_t = a + sh_d[tid];
      w = s_t - delta;
      w = (w > 0.0f) ? w : 0.0f;
    }
    float pw = w;
    #pragma unroll
    for (int off = 32; off > 0; off >>= 1) pw += __shfl_down(pw, off, 64);
    if (lane == 0) sh_redW[wid] = pw;
    __syncthreads();                                        // S3
    const float wsum = ((sh_redW[0] + sh_redW[1]) + (sh_redW[2] + sh_redW[3]))
                     + ((sh_redW[4] + sh_redW[5]) + (sh_redW[6] + sh_redW[7]));
    float aw = 0.0f;
    if (tid < rem) {
      aw = (rem <= 5) ? s_t : (w / (wsum + EPSF));
    }
    if (aw != 0.0f) {                      // <=5 nonzeros by construction
      int p = atomicAdd(&sh_nnz, 1);
      if (p < 8) { sh_cidx[p] = tid; sh_cw[p] = aw; }
    }
    if (i == 255 && tid < 256) {
      out[4096 + b * 256 + tid] = aw;      // final attn_w (w_sp, rem=256>5)
    }
    __syncthreads();                                        // S4

    // ---- Phase D: sparse attn gather, h update, d_new ----
    float pd = 0.0f;
    if (tid < 128) {
      int nz = sh_nnz; if (nz > 8) nz = 8;
      float attn = 0.0f;
      for (int k = 0; k < nz; ++k)
        attn = fmaf(sh_cw[k], hob[(size_t)sh_cidx[k] * 128 + tid], attn);
      float hn = sh_hcell[tid] + attn;
      sh_h[tid] = hn;
      hob[(size_t)rem * 128 + tid] = hn;
      pd = tanhf(hn) * sh_wb[tid];
      if (i == 255) out[b * 128 + tid] = attn;  // final attn_c
    }
    #pragma unroll
    for (int off = 32; off > 0; off >>= 1) pd += __shfl_down(pd, off, 64);
    if (lane == 0) sh_redD[wid] = pd;
    __syncthreads();                                        // S5
    if (tid == 0) {
      float dn = ((sh_redD[0] + sh_redD[1]) + (sh_redD[2] + sh_redD[3]))
               + ((sh_redD[4] + sh_redD[5]) + (sh_redD[6] + sh_redD[7]));
      sh_d[rem] = dn;
      float v = dn;                        // incremental sorted top-5 insert
      #pragma unroll
      for (int k = 0; k < 5; ++k) {
        if (v > sh_top5[k]) { float tmp = sh_top5[k]; sh_top5[k] = v; v = tmp; }
      }
    }
    // thread0's sh_d/top5 writes are consumed after next iter's S2 — safe.
  }
}

extern "C" void kernel_launch(void* const* d_in, const int* in_sizes, int n_in,
                              void* d_out, int out_size, void* d_ws, size_t ws_size,
                              hipStream_t stream) {
  const float* x    = (const float*)d_in[0];  // (32,256,64)
  const float* W_ih = (const float*)d_in[1];  // (512,64)
  const float* W_hh = (const float*)d_in[2];  // (512,128)
  const float* b_ih = (const float*)d_in[3];  // (512,)
  const float* b_hh = (const float*)d_in[4];  // (512,)
  const float* w_t  = (const float*)d_in[5];  // (256,1)
  float* out = (float*)d_out;                 // [0:4096) attn_c, [4096:12288) attn_w

  float* xw    = (float*)d_ws;                // 32*256*512 fp32 = 16 MB
  float* h_old = xw + (size_t)32 * 256 * 512; // 32*257*128 fp32 ≈ 4.2 MB

  xw_kernel<<<dim3(16, 32), 512, 0, stream>>>(x, W_ih, b_ih, b_hh, xw);
  lstm_attn<<<dim3(32), 512, 0, stream>>>(xw, W_hh, w_t, h_old, out);
}

// Round 2
// 739.169 us; speedup vs baseline: 1.1992x; 1.1992x over previous
//
#include <hip/hip_runtime.h>
#include <math.h>

#define NEGF -1000000000.0f
#define EPSF 1e-7f

// B=32, T=256, IN=64, H=128, 4H=512, TOP_K=5

__device__ __forceinline__ float fsigmoid(float x) {
  return 1.0f / (1.0f + __expf(-x));          // exp overflow -> 0: correct limit
}
__device__ __forceinline__ float ftanh(float x) {
  return 1.0f - 2.0f / (1.0f + __expf(2.0f * x));  // limits +-1: correct
}

// Kernel 1: xw[b][t][g] = sum_k x[b][t][k] * W_ih[g][k] + (b_ih[g]+b_hh[g])
// grid (16, 32) = (T/16, B), block 512 (one thread per gate)
__global__ __launch_bounds__(512) void xw_kernel(
    const float* __restrict__ x, const float* __restrict__ W_ih,
    const float* __restrict__ b_ih, const float* __restrict__ b_hh,
    float* __restrict__ xw)
{
  const int TT = 16;
  const int t0 = blockIdx.x * TT;
  const int b  = blockIdx.y;
  __shared__ float sx[16][64];
  for (int idx = threadIdx.x; idx < TT * 64; idx += 512) {
    int tt = idx >> 6, k = idx & 63;
    sx[tt][k] = x[(size_t)(b * 256 + t0 + tt) * 64 + k];
  }
  __syncthreads();
  const int g = threadIdx.x;
  float w[64];
  {
    const float4* wr = (const float4*)(W_ih + g * 64);
    #pragma unroll
    for (int q = 0; q < 16; ++q) {
      float4 v = wr[q];
      w[4*q+0] = v.x; w[4*q+1] = v.y; w[4*q+2] = v.z; w[4*q+3] = v.w;
    }
  }
  const float bias = b_ih[g] + b_hh[g];
  for (int tt = 0; tt < TT; ++tt) {
    float acc = bias;
    #pragma unroll
    for (int k = 0; k < 64; ++k) acc = fmaf(w[k], sx[tt][k], acc);
    xw[(size_t)(b * 256 + t0 + tt) * 512 + g] = acc;
  }
}

// Kernel 2: full recurrence, one block per batch element, 1024 threads.
// Thread t owns (gate g = t&511, k-half = t>>9): 64 W_hh weights in VGPRs.
// h_old history lives entirely in LDS (257*128 fp32 = 131 KB).
__global__ __launch_bounds__(1024) void lstm_attn(
    const float* __restrict__ xw, const float* __restrict__ W_hh,
    const float* __restrict__ w_t, float* __restrict__ out)
{
  const int b    = blockIdx.x;
  const int tid  = threadIdx.x;
  const int lane = tid & 63;
  const int wid  = tid >> 6;
  const int g    = tid & 511;
  const int half = tid >> 9;          // uniform per wave

  __shared__ float ho[257 * 128];     // h history   (131584 B)
  __shared__ float sh_part[1024];     // gate partials
  __shared__ float sh_h[128];
  __shared__ float sh_hcell[128];
  __shared__ float sh_d[257];
  __shared__ float sh_wa[128];
  __shared__ float sh_wb[128];
  __shared__ float sh_top5[5];
  __shared__ float sh_redA[2];
  __shared__ float sh_redW[4];
  __shared__ float sh_redD[2];
  __shared__ int   sh_nnz;
  __shared__ int   sh_cidx[8];
  __shared__ float sh_cw[8];

  // one-time: 64 weights of W_hh row g (half-th half of K) into VGPRs
  float wv[64];
  {
    const float4* wr = (const float4*)(W_hh + (size_t)g * 128 + (half << 6));
    #pragma unroll
    for (int q = 0; q < 16; ++q) {
      float4 v = wr[q];
      wv[4*q+0] = v.x; wv[4*q+1] = v.y; wv[4*q+2] = v.z; wv[4*q+3] = v.w;
    }
  }
  if (tid < 128) {
    sh_h[tid]  = 0.0f;
    sh_wa[tid] = w_t[tid];
    sh_wb[tid] = w_t[128 + tid];
    ho[tid]    = 0.0f;                // row 0 = h(-1) = zeros
  }
  if (tid == 0) {
    sh_d[0] = 0.0f;                   // tanh(0)·w_b
    sh_top5[0] = 0.0f;
    sh_top5[1] = sh_top5[2] = sh_top5[3] = sh_top5[4] = NEGF;
  }
  float c_reg = 0.0f;                 // c[j] lives in thread j (tid<128)
  __syncthreads();

  const float* xwb = xw + (size_t)b * 256 * 512;
  float xcur = (half == 0) ? xwb[g] : 0.0f;   // prefetched xw for step 0

  for (int i = 0; i < 256; ++i) {
    const int rem = i + 1;

    // ---- Phase A: gate partials (64 FMAs from VGPR weights) ----
    float acc0 = xcur, acc1 = 0.0f, acc2 = 0.0f, acc3 = 0.0f;
    if (half == 0 && i < 255) xcur = xwb[(size_t)(i + 1) * 512 + g]; // prefetch
    {
      const float* hh = sh_h + (half << 6);   // wave-broadcast LDS reads
      #pragma unroll
      for (int k = 0; k < 64; k += 4) {
        acc0 = fmaf(wv[k+0], hh[k+0], acc0);
        acc1 = fmaf(wv[k+1], hh[k+1], acc1);
        acc2 = fmaf(wv[k+2], hh[k+2], acc2);
        acc3 = fmaf(wv[k+3], hh[k+3], acc3);
      }
    }
    sh_part[tid] = (acc0 + acc1) + (acc2 + acc3);
    __syncthreads();                                        // S1

    // ---- Phase B: LSTM cell + a = tanh(h_cell)·w_a partial ----
    if (tid == 0) sh_nnz = 0;
    float pa = 0.0f;
    if (tid < 128) {
      float gi = fsigmoid(sh_part[tid      ] + sh_part[tid + 512]);
      float gf = fsigmoid(sh_part[tid + 128] + sh_part[tid + 640]);
      float gg = ftanh   (sh_part[tid + 256] + sh_part[tid + 768]);
      float go = fsigmoid(sh_part[tid + 384] + sh_part[tid + 896]);
      c_reg = gf * c_reg + gi * gg;
      float hc = go * ftanh(c_reg);
      sh_hcell[tid] = hc;
      pa = ftanh(hc) * sh_wa[tid];
    }
    if (wid < 2) {
      #pragma unroll
      for (int off = 32; off > 0; off >>= 1) pa += __shfl_down(pa, off, 64);
      if (lane == 0) sh_redA[wid] = pa;
    }
    __syncthreads();                                        // S2

    // ---- Phase C: scores, sparse-candidate collection (unnormalized) ----
    const float a     = sh_redA[0] + sh_redA[1];
    const float delta = (a + sh_top5[4]) + EPSF;
    float s_t = 0.0f, w = 0.0f;
    if (tid < rem) {                 // rem <= 256 so only waves 0..3 active
      s_t = a + sh_d[tid];
      w = s_t - delta;
      w = (w > 0.0f) ? w : 0.0f;
      if (rem <= 5) {
        int p = atomicAdd(&sh_nnz, 1);
        if (p < 8) { sh_cidx[p] = tid; sh_cw[p] = s_t; }   // attn_w = s branch
      } else if (w > 0.0f) {                               // <=4 by construction
        int p = atomicAdd(&sh_nnz, 1);
        if (p < 8) { sh_cidx[p] = tid; sh_cw[p] = w; }
      }
    }
    float pw = w;
    if (wid < 4) {
      #pragma unroll
      for (int off = 32; off > 0; off >>= 1) pw += __shfl_down(pw, off, 64);
      if (lane == 0) sh_redW[wid] = pw;
    }
    __syncthreads();                                        // S3 (merged)

    // ---- Phase D: sparse gather from LDS history, h update, d_new ----
    const float wsum = (sh_redW[0] + sh_redW[1]) + (sh_redW[2] + sh_redW[3]);
    const float inv  = (rem <= 5) ? 1.0f : 1.0f / (wsum + EPSF);
    float pd = 0.0f;
    if (tid < 128) {
      int nz = sh_nnz; if (nz > 8) nz = 8;
      float attn = 0.0f;
      for (int k = 0; k < nz; ++k)
        attn = fmaf(sh_cw[k], ho[sh_cidx[k] * 128 + tid], attn);
      attn *= inv;
      float hn = sh_hcell[tid] + attn;
      sh_h[tid] = hn;
      ho[rem * 128 + tid] = hn;
      pd = ftanh(hn) * sh_wb[tid];
      if (i == 255) out[b * 128 + tid] = attn;             // final attn_c
    }
    if (i == 255 && tid < 256) {
      out[4096 + b * 256 + tid] = w * inv;                 // final attn_w
    }
    if (wid < 2) {
      #pragma unroll
      for (int off = 32; off > 0; off >>= 1) pd += __shfl_down(pd, off, 64);
      if (lane == 0) sh_redD[wid] = pd;
    }
    __syncthreads();                                        // S4
    if (tid == 0) {
      float dn = sh_redD[0] + sh_redD[1];
      sh_d[rem] = dn;
      float v = dn;                  // incremental sorted top-5 insert
      #pragma unroll
      for (int k = 0; k < 5; ++k) {
        if (v > sh_top5[k]) { float tmp = sh_top5[k]; sh_top5[k] = v; v = tmp; }
      }
    }
    // thread0's writes ordered before its S1 arrival; consumed after next S2.
  }
}

extern "C" void kernel_launch(void* const* d_in, const int* in_sizes, int n_in,
                              void* d_out, int out_size, void* d_ws, size_t ws_size,
                              hipStream_t stream) {
  const float* x    = (const float*)d_in[0];  // (32,256,64)
  const float* W_ih = (const float*)d_in[1];  // (512,64)
  const float* W_hh = (const float*)d_in[2];  // (512,128)
  const float* b_ih = (const float*)d_in[3];  // (512,)
  const float* b_hh = (const float*)d_in[4];  // (512,)
  const float* w_t  = (const float*)d_in[5];  // (256,1)
  float* out = (float*)d_out;                 // [0:4096) attn_c, [4096:12288) attn_w

  float* xw = (float*)d_ws;                   // 32*256*512 fp32 = 16 MB

  xw_kernel<<<dim3(16, 32), 512, 0, stream>>>(x, W_ih, b_ih, b_hh, xw);
  lstm_attn<<<dim3(32), 1024, 0, stream>>>(xw, W_hh, w_t, out);
}

// Round 3
// 674.249 us; speedup vs baseline: 1.3147x; 1.0963x over previous
//
#include <hip/hip_runtime.h>
#include <math.h>

#define NEGF -1000000000.0f
#define EPSF 1e-7f

// B=32, T=256, IN=64, H=128, 4H=512, TOP_K=5

__device__ __forceinline__ float fsigmoid(float x) {
  return 1.0f / (1.0f + __expf(-x));               // overflow -> correct limit
}
__device__ __forceinline__ float ftanh(float x) {
  return 1.0f - 2.0f / (1.0f + __expf(2.0f * x));  // limits +-1: correct
}

// Kernel 1: xw[b][t][g] = sum_k x[b][t][k] * W_ih[g][k] + (b_ih[g]+b_hh[g])
// grid (16, 32) = (T/16, B), block 512 (one thread per gate).
// W_ih row held in 16 NAMED float4s -> guaranteed VGPR-resident (no array).
__global__ __launch_bounds__(512, 2) void xw_kernel(
    const float* __restrict__ x, const float* __restrict__ W_ih,
    const float* __restrict__ b_ih, const float* __restrict__ b_hh,
    float* __restrict__ xw)
{
  const int TT = 16;
  const int t0 = blockIdx.x * TT;
  const int b  = blockIdx.y;
  __shared__ float sx[16][64];
  for (int idx = threadIdx.x; idx < TT * 64; idx += 512) {
    int tt = idx >> 6, k = idx & 63;
    sx[tt][k] = x[(size_t)(b * 256 + t0 + tt) * 64 + k];
  }
  const int g = threadIdx.x;
  const float4* wr = (const float4*)(W_ih + g * 64);
  float4 w0 = wr[0], w1 = wr[1], w2 = wr[2],  w3 = wr[3],
         w4 = wr[4], w5 = wr[5], w6 = wr[6],  w7 = wr[7],
         w8 = wr[8], w9 = wr[9], w10 = wr[10], w11 = wr[11],
         w12 = wr[12], w13 = wr[13], w14 = wr[14], w15 = wr[15];
  const float bias = b_ih[g] + b_hh[g];
  __syncthreads();
  for (int tt = 0; tt < TT; ++tt) {
    const float4* sx4 = (const float4*)(&sx[tt][0]);
    float a0 = bias, a1 = 0.0f, a2 = 0.0f, a3 = 0.0f;
#define XSTEP(q) { float4 hv = sx4[q]; \
    a0 = fmaf(w##q.x, hv.x, a0); a1 = fmaf(w##q.y, hv.y, a1); \
    a2 = fmaf(w##q.z, hv.z, a2); a3 = fmaf(w##q.w, hv.w, a3); }
    XSTEP(0) XSTEP(1) XSTEP(2) XSTEP(3) XSTEP(4) XSTEP(5) XSTEP(6) XSTEP(7)
    XSTEP(8) XSTEP(9) XSTEP(10) XSTEP(11) XSTEP(12) XSTEP(13) XSTEP(14) XSTEP(15)
#undef XSTEP
    xw[(size_t)(b * 256 + t0 + tt) * 512 + g] = (a0 + a1) + (a2 + a3);
  }
}

// Kernel 2: full recurrence, one block per batch element, 1024 threads.
// Thread t: K-chunk q = t>>8 (32 of the 128 h values), gates (t&255) and
// (t&255)+256 -> 64 weights in 16 NAMED float4s (VGPR-resident).
// Each h chunk read once from LDS feeds TWO gates (halves broadcast reads).
// h_old history lives entirely in LDS (257*128 fp32 = 131 KB).
__global__ __launch_bounds__(1024, 4) void lstm_attn(
    const float* __restrict__ xw, const float* __restrict__ W_hh,
    const float* __restrict__ w_t, float* __restrict__ out)
{
  const int b    = blockIdx.x;
  const int tid  = threadIdx.x;
  const int lane = tid & 63;
  const int wid  = tid >> 6;
  const int q    = tid >> 8;          // K-chunk 0..3 (wave-uniform)
  const int gg   = tid & 255;
  const int gA   = gg;                // gate rows
  const int gB   = gg + 256;

  __shared__ float ho[257 * 128];     // h history (131584 B)
  __shared__ float sh_part[4 * 512];  // gate partials [q][gate]
  __shared__ float sh_h[128];
  __shared__ float sh_hcell[128];
  __shared__ float sh_d[257];
  __shared__ float sh_wa[128];
  __shared__ float sh_wb[128];
  __shared__ float sh_top5[5];
  __shared__ float sh_redA[2];
  __shared__ float sh_redW[4];
  __shared__ float sh_redD[2];
  __shared__ int   sh_nnz;
  __shared__ int   sh_cidx[8];
  __shared__ float sh_cw[8];

  // one-time weight load: 16 named float4 = 64 VGPRs, no spillable array
  const float4* pA = (const float4*)(W_hh + (size_t)gA * 128 + (q << 5));
  const float4* pB = (const float4*)(W_hh + (size_t)gB * 128 + (q << 5));
  float4 wA0 = pA[0], wA1 = pA[1], wA2 = pA[2], wA3 = pA[3],
         wA4 = pA[4], wA5 = pA[5], wA6 = pA[6], wA7 = pA[7];
  float4 wB0 = pB[0], wB1 = pB[1], wB2 = pB[2], wB3 = pB[3],
         wB4 = pB[4], wB5 = pB[5], wB6 = pB[6], wB7 = pB[7];

  if (tid < 128) {
    sh_h[tid]  = 0.0f;
    sh_wa[tid] = w_t[tid];
    sh_wb[tid] = w_t[128 + tid];
    ho[tid]    = 0.0f;                // row 0 = h(-1) = zeros
  }
  if (tid == 0) {
    sh_d[0] = 0.0f;                   // tanh(0)·w_b
    sh_top5[0] = 0.0f;
    sh_top5[1] = sh_top5[2] = sh_top5[3] = sh_top5[4] = NEGF;
  }
  float c_reg = 0.0f;                 // c[j] lives in thread j (tid<128)
  __syncthreads();

  const float* xwb = xw + (size_t)b * 256 * 512;
  float xcurA = 0.0f, xcurB = 0.0f;
  if (q == 0) { xcurA = xwb[gA]; xcurB = xwb[gB]; }   // step-0 prefetch

  for (int i = 0; i < 256; ++i) {
    const int rem = i + 1;

    // ---- Phase A: gate partials (64 FMAs from named-VGPR weights) ----
    float aA0 = xcurA, aA1 = 0.0f, aB0 = xcurB, aB1 = 0.0f;
    if (q == 0 && i < 255) {          // prefetch next step's xw
      xcurA = xwb[(size_t)(i + 1) * 512 + gA];
      xcurB = xwb[(size_t)(i + 1) * 512 + gB];
    }
    const float4* hh4 = (const float4*)(sh_h + (q << 5));
#define LSTEP(j) { float4 hv = hh4[j]; \
    aA0 = fmaf(wA##j.x, hv.x, aA0); aA1 = fmaf(wA##j.y, hv.y, aA1); \
    aA0 = fmaf(wA##j.z, hv.z, aA0); aA1 = fmaf(wA##j.w, hv.w, aA1); \
    aB0 = fmaf(wB##j.x, hv.x, aB0); aB1 = fmaf(wB##j.y, hv.y, aB1); \
    aB0 = fmaf(wB##j.z, hv.z, aB0); aB1 = fmaf(wB##j.w, hv.w, aB1); }
    LSTEP(0) LSTEP(1) LSTEP(2) LSTEP(3) LSTEP(4) LSTEP(5) LSTEP(6) LSTEP(7)
#undef LSTEP
    sh_part[(q << 9) + gA] = aA0 + aA1;
    sh_part[(q << 9) + gB] = aB0 + aB1;
    __syncthreads();                                        // S1

    // ---- Phase B: LSTM cell + a = tanh(h_cell)·w_a partial ----
    if (tid == 0) sh_nnz = 0;
    float pa = 0.0f;
    if (tid < 128) {
      float gi = ((sh_part[tid      ] + sh_part[tid +  512]) +
                  (sh_part[tid + 1024] + sh_part[tid + 1536]));
      float gf = ((sh_part[tid + 128] + sh_part[tid +  640]) +
                  (sh_part[tid + 1152] + sh_part[tid + 1664]));
      float gG = ((sh_part[tid + 256] + sh_part[tid +  768]) +
                  (sh_part[tid + 1280] + sh_part[tid + 1792]));
      float go = ((sh_part[tid + 384] + sh_part[tid +  896]) +
                  (sh_part[tid + 1408] + sh_part[tid + 1920]));
      gi = fsigmoid(gi); gf = fsigmoid(gf); gG = ftanh(gG); go = fsigmoid(go);
      c_reg = gf * c_reg + gi * gG;
      float hc = go * ftanh(c_reg);
      sh_hcell[tid] = hc;
      pa = ftanh(hc) * sh_wa[tid];
    }
    if (wid < 2) {
      #pragma unroll
      for (int off = 32; off > 0; off >>= 1) pa += __shfl_down(pa, off, 64);
      if (lane == 0) sh_redA[wid] = pa;
    }
    __syncthreads();                                        // S2

    // ---- Phase C: scores, sparse-candidate collection (unnormalized) ----
    const float a     = sh_redA[0] + sh_redA[1];
    const float delta = (a + sh_top5[4]) + EPSF;
    float s_t = 0.0f, w = 0.0f;
    if (tid < rem) {                 // rem <= 256 so only waves 0..3 active
      s_t = a + sh_d[tid];
      w = s_t - delta;
      w = (w > 0.0f) ? w : 0.0f;
      if (rem <= 5) {
        int p = atomicAdd(&sh_nnz, 1);
        if (p < 8) { sh_cidx[p] = tid; sh_cw[p] = s_t; }   // attn_w = s branch
      } else if (w > 0.0f) {                               // <=4 by construction
        int p = atomicAdd(&sh_nnz, 1);
        if (p < 8) { sh_cidx[p] = tid; sh_cw[p] = w; }
      }
    }
    float pw = w;
    if (wid < 4) {
      #pragma unroll
      for (int off = 32; off > 0; off >>= 1) pw += __shfl_down(pw, off, 64);
      if (lane == 0) sh_redW[wid] = pw;
    }
    __syncthreads();                                        // S3

    // ---- Phase D: sparse gather from LDS history, h update, d_new ----
    const float wsum = (sh_redW[0] + sh_redW[1]) + (sh_redW[2] + sh_redW[3]);
    const float inv  = (rem <= 5) ? 1.0f : 1.0f / (wsum + EPSF);
    float pd = 0.0f;
    if (tid < 128) {
      int nz = sh_nnz; if (nz > 8) nz = 8;
      float attn = 0.0f;
      for (int k = 0; k < nz; ++k)
        attn = fmaf(sh_cw[k], ho[sh_cidx[k] * 128 + tid], attn);
      attn *= inv;
      float hn = sh_hcell[tid] + attn;
      sh_h[tid] = hn;
      ho[rem * 128 + tid] = hn;
      pd = ftanh(hn) * sh_wb[tid];
      if (i == 255) out[b * 128 + tid] = attn;             // final attn_c
    }
    if (i == 255 && tid < 256) {
      out[4096 + b * 256 + tid] = w * inv;                 // final attn_w
    }
    if (wid < 2) {
      #pragma unroll
      for (int off = 32; off > 0; off >>= 1) pd += __shfl_down(pd, off, 64);
      if (lane == 0) sh_redD[wid] = pd;
    }
    __syncthreads();                                        // S4
    if (tid == 0) {
      float dn = sh_redD[0] + sh_redD[1];
      sh_d[rem] = dn;
      float v = dn;                  // incremental sorted top-5 insert
      #pragma unroll
      for (int k = 0; k < 5; ++k) {
        if (v > sh_top5[k]) { float tmp = sh_top5[k]; sh_top5[k] = v; v = tmp; }
      }
    }
    // thread0's writes are separated from their readers by S1+S2 -> safe.
  }
}

extern "C" void kernel_launch(void* const* d_in, const int* in_sizes, int n_in,
                              void* d_out, int out_size, void* d_ws, size_t ws_size,
                              hipStream_t stream) {
  const float* x    = (const float*)d_in[0];  // (32,256,64)
  const float* W_ih = (const float*)d_in[1];  // (512,64)
  const float* W_hh = (const float*)d_in[2];  // (512,128)
  const float* b_ih = (const float*)d_in[3];  // (512,)
  const float* b_hh = (const float*)d_in[4];  // (512,)
  const float* w_t  = (const float*)d_in[5];  // (256,1)
  float* out = (float*)d_out;                 // [0:4096) attn_c, [4096:12288) attn_w

  float* xw = (float*)d_ws;                   // 32*256*512 fp32 = 16 MB

  xw_kernel<<<dim3(16, 32), 512, 0, stream>>>(x, W_ih, b_ih, b_hh, xw);
  lstm_attn<<<dim3(32), 1024, 0, stream>>>(xw, W_hh, w_t, out);
}